// Round 13
// baseline (244.513 us; speedup 1.0000x reference)
//
#include <hip/hip_runtime.h>
#include <hip/hip_bf16.h>
#include <cstdint>
#include <cstddef>

#define LEAKY(x) ((x) > 0.f ? (x) : 0.2f * (x))

#define NBUCK 128          // buckets of 1024 nodes (N=100000 -> 98 used)
#define BSH   10           // bucket shift
#define BPAD  16           // pad counters one 64B line apart
#define WPAD  136          // LDS W row pad (272B stride -> near-conflict-free frag reads)

typedef float        f32x4  __attribute__((ext_vector_type(4)));
typedef unsigned int u32x4  __attribute__((ext_vector_type(4)));
typedef short        bf16x8 __attribute__((ext_vector_type(8)));

__device__ __forceinline__ float readlane_f(float v, int l) {
    return __int_as_float(__builtin_amdgcn_readlane(__float_as_int(v), l));
}
// round-to-nearest-even fp32 -> bf16 bits
__device__ __forceinline__ unsigned short f2bf(float f) {
    unsigned x = __float_as_uint(f);
    return (unsigned short)((x + 0x7fffu + ((x >> 16) & 1u)) >> 16);
}
__device__ __forceinline__ float bf_lo(unsigned u) { return __uint_as_float(u << 16); }
__device__ __forceinline__ float bf_hi(unsigned u) { return __uint_as_float(u & 0xffff0000u); }

__device__ __forceinline__ bf16x8 as_bf16x8(u32x4 u) {
    union { u32x4 u4; bf16x8 b; } cv;
    cv.u4 = u;
    return cv.b;
}

// ---------------------------------------------------------------- bucket histogram
__global__ void hist_bucket(const int* __restrict__ ei, int E, int* __restrict__ bcnt,
                            int nblocks) {
    __shared__ int bl[NBUCK];
    for (int i = threadIdx.x; i < NBUCK; i += 256) bl[i] = 0;
    __syncthreads();
    const int stride = nblocks * 256;
    for (int e = blockIdx.x * 256 + threadIdx.x; e < E; e += stride)
        atomicAdd(&bl[ei[E + e] >> BSH], 1);
    __syncthreads();
    for (int i = threadIdx.x; i < NBUCK; i += 256) {
        int c = bl[i];
        if (c) atomicAdd(&bcnt[i * BPAD], c);
    }
}

// bucket exclusive scan (tiny)
__global__ void scan_bucket(const int* __restrict__ bcnt, int* __restrict__ bcur,
                            int* __restrict__ bstart, int* __restrict__ offsets, int n) {
    if (threadIdx.x == 0 && blockIdx.x == 0) {
        int run = 0;
        for (int b = 0; b < NBUCK; ++b) {
            int v = bcnt[b * BPAD];
            bcur[b * BPAD] = run;
            bstart[b] = run;
            run += v;
        }
        bstart[NBUCK] = run;
        offsets[n] = run;
    }
}

// ---------------------------------------------------------------- K1: pass1 (edge binning) || MFMA GEMM1 + epilogue
__global__ __launch_bounds__(256) void fused_gemm1_pass1(
    const float* __restrict__ x, const float* __restrict__ W1, int M,
    const float* __restrict__ att_src, const float* __restrict__ att_dst,
    unsigned* __restrict__ hpk, float* __restrict__ asrc, float* __restrict__ adst,
    const int* __restrict__ ei, int E, int* __restrict__ bcur, int2* __restrict__ ebuf,
    int p1Blocks) {
    const int tid = threadIdx.x;
    if ((int)blockIdx.x < p1Blocks) {
        __shared__ int bcnt_l[NBUCK];
        __shared__ int bbase_l[NBUCK];
        const int e0 = (int)blockIdx.x * 4096;
        const int ecnt = min(4096, E - e0);
        for (int i = tid; i < NBUCK; i += 256) bcnt_l[i] = 0;
        __syncthreads();
        for (int i = tid; i < ecnt; i += 256)
            atomicAdd(&bcnt_l[ei[E + e0 + i] >> BSH], 1);
        __syncthreads();
        if (tid < NBUCK) {
            int c = bcnt_l[tid];
            bbase_l[tid] = c ? atomicAdd(&bcur[tid * BPAD], c) : 0;
            bcnt_l[tid] = 0;
        }
        __syncthreads();
        for (int i = tid; i < ecnt; i += 256) {
            int s = ei[e0 + i];
            int d = ei[E + e0 + i];
            int b = d >> BSH;
            int l = atomicAdd(&bcnt_l[b], 1);
            ebuf[bbase_l[b] + l] = make_int2(s, d);
        }
    } else {
        __shared__ unsigned short Wt[128][WPAD];   // [col][k], bf16
        for (int i = tid; i < 128 * 128; i += 256) {
            int k = i >> 7, c = i & 127;
            Wt[c][k] = f2bf(W1[i]);
        }
        __syncthreads();
        const int gb = (int)blockIdx.x - p1Blocks;
        const int lane = tid & 63;
        const int li = lane & 15, g = lane >> 4;
        const int row0 = gb * 64 + (tid >> 6) * 16;
        const int arow = min(row0 + li, M - 1);
        f32x4 acc[8];
#pragma unroll
        for (int ct = 0; ct < 8; ++ct) acc[ct] = (f32x4)(0.f);
        const float* ap = x + (size_t)arow * 128 + g * 8;
#pragma unroll
        for (int ks = 0; ks < 4; ++ks) {
            float4 a0 = *(const float4*)(ap + ks * 32);
            float4 a1 = *(const float4*)(ap + ks * 32 + 4);
            u32x4 af;
            af.x = (unsigned)f2bf(a0.x) | ((unsigned)f2bf(a0.y) << 16);
            af.y = (unsigned)f2bf(a0.z) | ((unsigned)f2bf(a0.w) << 16);
            af.z = (unsigned)f2bf(a1.x) | ((unsigned)f2bf(a1.y) << 16);
            af.w = (unsigned)f2bf(a1.z) | ((unsigned)f2bf(a1.w) << 16);
            bf16x8 av = as_bf16x8(af);
#pragma unroll
            for (int ct = 0; ct < 8; ++ct) {
                bf16x8 bv = *(const bf16x8*)&Wt[ct * 16 + li][ks * 32 + g * 8];
                acc[ct] = __builtin_amdgcn_mfma_f32_16x16x32_bf16(av, bv, acc[ct], 0, 0, 0);
            }
        }
        // epilogue: scores + bf16 pack. head0 = cols 0..63 (ct 0..3), head1 = 64..127.
        float asv[8], adv[8];
#pragma unroll
        for (int ct = 0; ct < 8; ++ct) {
            asv[ct] = att_src[ct * 16 + li];
            adv[ct] = att_dst[ct * 16 + li];
        }
#pragma unroll
        for (int reg = 0; reg < 4; ++reg) {
            int r = row0 + g * 4 + reg;
            float ps0 = 0.f, pd0 = 0.f, ps1 = 0.f, pd1 = 0.f;
#pragma unroll
            for (int ct = 0; ct < 4; ++ct) {
                ps0 = fmaf(acc[ct][reg], asv[ct], ps0);
                pd0 = fmaf(acc[ct][reg], adv[ct], pd0);
                ps1 = fmaf(acc[ct + 4][reg], asv[ct + 4], ps1);
                pd1 = fmaf(acc[ct + 4][reg], adv[ct + 4], pd1);
            }
#pragma unroll
            for (int m = 8; m > 0; m >>= 1) {
                ps0 += __shfl_xor(ps0, m);
                pd0 += __shfl_xor(pd0, m);
                ps1 += __shfl_xor(ps1, m);
                pd1 += __shfl_xor(pd1, m);
            }
            if (r < M) {
                if (li == 0) {
                    asrc[2 * r] = ps0; asrc[2 * r + 1] = ps1;
                    adst[2 * r] = pd0; adst[2 * r + 1] = pd1;
                }
#pragma unroll
                for (int ct = 0; ct < 4; ++ct)
                    hpk[(size_t)r * 64 + ct * 16 + li] =
                        (unsigned)f2bf(acc[ct][reg]) | ((unsigned)f2bf(acc[ct + 4][reg]) << 16);
            }
        }
    }
}

// ---------------------------------------------------------------- K2: per-bucket offsets + localized scatter
__global__ __launch_bounds__(256) void pass2_build(
    const int2* __restrict__ ebuf, const int* __restrict__ bstart, int* __restrict__ offsets,
    int* __restrict__ csr, int N) {
    __shared__ int lcur[1 << BSH];
    __shared__ int ssum[256];
    const int b = blockIdx.x;
    const int dbase = b << BSH;
    const int tid = threadIdx.x;
    for (int i = tid; i < (1 << BSH); i += 256) lcur[i] = 0;
    __syncthreads();
    const int es = bstart[b], ee = bstart[b + 1];
    for (int i = es + tid; i < ee; i += 256)
        atomicAdd(&lcur[ebuf[i].y - dbase], 1);
    __syncthreads();
    const int base_ = tid * 4;
    int v0 = lcur[base_], v1 = lcur[base_ + 1], v2 = lcur[base_ + 2], v3 = lcur[base_ + 3];
    ssum[tid] = v0 + v1 + v2 + v3;
    __syncthreads();
    for (int o = 1; o < 256; o <<= 1) {
        int add = (tid >= o) ? ssum[tid - o] : 0;
        __syncthreads();
        ssum[tid] += add;
        __syncthreads();
    }
    int excl = (tid ? ssum[tid - 1] : 0) + bstart[b];
    int c0 = excl, c1 = c0 + v0, c2 = c1 + v1, c3 = c2 + v2;
    lcur[base_] = c0; lcur[base_ + 1] = c1; lcur[base_ + 2] = c2; lcur[base_ + 3] = c3;
    int idx = dbase + base_;
    if (idx < N)     offsets[idx] = c0;
    if (idx + 1 < N) offsets[idx + 1] = c1;
    if (idx + 2 < N) offsets[idx + 2] = c2;
    if (idx + 3 < N) offsets[idx + 3] = c3;
    __syncthreads();
    for (int i = es + tid; i < ee; i += 256) {
        int2 p = ebuf[i];
        int pos = atomicAdd(&lcur[p.y - dbase], 1);
        csr[pos] = p.x;
    }
}

// ---------------------------------------------------------------- K3: MFMA GEMM2 + epilogue
__global__ __launch_bounds__(256) void gemm2_epi(
    const unsigned short* __restrict__ A, const float* __restrict__ W2, int M,
    const float* __restrict__ att_src, const float* __restrict__ att_dst,
    unsigned short* __restrict__ hb, float* __restrict__ asrc, float* __restrict__ adst) {
    __shared__ unsigned short Wt[64][WPAD];
    const int tid = threadIdx.x;
    for (int i = tid; i < 128 * 64; i += 256) {
        int k = i >> 6, c = i & 63;
        Wt[c][k] = f2bf(W2[i]);
    }
    __syncthreads();
    const int lane = tid & 63;
    const int li = lane & 15, g = lane >> 4;
    const int row0 = blockIdx.x * 64 + (tid >> 6) * 16;
    const int arow = min(row0 + li, M - 1);
    f32x4 acc[4];
#pragma unroll
    for (int ct = 0; ct < 4; ++ct) acc[ct] = (f32x4)(0.f);
    const unsigned short* ap = A + (size_t)arow * 128 + g * 8;
#pragma unroll
    for (int ks = 0; ks < 4; ++ks) {
        bf16x8 av = *(const bf16x8*)(ap + ks * 32);
#pragma unroll
        for (int ct = 0; ct < 4; ++ct) {
            bf16x8 bv = *(const bf16x8*)&Wt[ct * 16 + li][ks * 32 + g * 8];
            acc[ct] = __builtin_amdgcn_mfma_f32_16x16x32_bf16(av, bv, acc[ct], 0, 0, 0);
        }
    }
    float asv[4], adv[4];
#pragma unroll
    for (int ct = 0; ct < 4; ++ct) {
        asv[ct] = att_src[ct * 16 + li];
        adv[ct] = att_dst[ct * 16 + li];
    }
#pragma unroll
    for (int reg = 0; reg < 4; ++reg) {
        int r = row0 + g * 4 + reg;
        float ps = 0.f, pd = 0.f;
#pragma unroll
        for (int ct = 0; ct < 4; ++ct) {
            ps = fmaf(acc[ct][reg], asv[ct], ps);
            pd = fmaf(acc[ct][reg], adv[ct], pd);
        }
#pragma unroll
        for (int m = 8; m > 0; m >>= 1) {
            ps += __shfl_xor(ps, m);
            pd += __shfl_xor(pd, m);
        }
        if (r < M) {
            if (li == 0) { asrc[r] = ps; adst[r] = pd; }
#pragma unroll
            for (int ct = 0; ct < 4; ++ct)
                hb[(size_t)r * 64 + ct * 16 + li] = f2bf(acc[ct][reg]);
        }
    }
}

// ---------------------------------------------------------------- agg layer1: no-max softmax + aggregate, bf16 out
// j-loop: 8 gathers issued before use (deep MLP) then 16 FMAs.
__global__ void agg_layer1(const unsigned* __restrict__ hpk, const float* __restrict__ asrc,
                           const float* __restrict__ adst, const int* __restrict__ offs,
                           const int* __restrict__ csr, const float* __restrict__ bias,
                           unsigned short* __restrict__ out1b, int N) {
    int node = (blockIdx.x * blockDim.x + threadIdx.x) >> 6;
    int lane = threadIdx.x & 63;
    if (node >= N) return;
    int off = offs[node], end = offs[node + 1];
    float ad0 = adst[2 * node], ad1 = adst[2 * node + 1];
    float ws0 = __expf(fminf(LEAKY(asrc[2 * node] + ad0), 60.f));
    float ws1 = __expf(fminf(LEAKY(asrc[2 * node + 1] + ad1), 60.f));
    float sum0 = ws0, sum1 = ws1;
    float acc0, acc1;
    {
        unsigned u = hpk[(size_t)node * 64 + lane];
        acc0 = ws0 * bf_lo(u);
        acc1 = ws1 * bf_hi(u);
    }
    for (int chunk = off; chunk < end; chunk += 64) {
        int e = chunk + lane;
        int s = 0;
        float w0 = 0.f, w1 = 0.f;
        if (e < end) {
            s = csr[e];
            float2 as = *(const float2*)&asrc[2 * s];
            w0 = __expf(fminf(LEAKY(as.x + ad0), 60.f));
            w1 = __expf(fminf(LEAKY(as.y + ad1), 60.f));
        }
        float t0 = w0, t1 = w1;
#pragma unroll
        for (int o = 32; o > 0; o >>= 1) {
            t0 += __shfl_xor(t0, o);
            t1 += __shfl_xor(t1, o);
        }
        sum0 += t0; sum1 += t1;

        int cnt = min(64, end - chunk);
        int j = 0;
        for (; j + 8 <= cnt; j += 8) {
            int sj0 = __builtin_amdgcn_readlane(s, j);
            int sj1 = __builtin_amdgcn_readlane(s, j + 1);
            int sj2 = __builtin_amdgcn_readlane(s, j + 2);
            int sj3 = __builtin_amdgcn_readlane(s, j + 3);
            int sj4 = __builtin_amdgcn_readlane(s, j + 4);
            int sj5 = __builtin_amdgcn_readlane(s, j + 5);
            int sj6 = __builtin_amdgcn_readlane(s, j + 6);
            int sj7 = __builtin_amdgcn_readlane(s, j + 7);
            unsigned u0 = hpk[(size_t)sj0 * 64 + lane];
            unsigned u1 = hpk[(size_t)sj1 * 64 + lane];
            unsigned u2 = hpk[(size_t)sj2 * 64 + lane];
            unsigned u3 = hpk[(size_t)sj3 * 64 + lane];
            unsigned u4 = hpk[(size_t)sj4 * 64 + lane];
            unsigned u5 = hpk[(size_t)sj5 * 64 + lane];
            unsigned u6 = hpk[(size_t)sj6 * 64 + lane];
            unsigned u7 = hpk[(size_t)sj7 * 64 + lane];
            acc0 = fmaf(readlane_f(w0, j),     bf_lo(u0), acc0);
            acc1 = fmaf(readlane_f(w1, j),     bf_hi(u0), acc1);
            acc0 = fmaf(readlane_f(w0, j + 1), bf_lo(u1), acc0);
            acc1 = fmaf(readlane_f(w1, j + 1), bf_hi(u1), acc1);
            acc0 = fmaf(readlane_f(w0, j + 2), bf_lo(u2), acc0);
            acc1 = fmaf(readlane_f(w1, j + 2), bf_hi(u2), acc1);
            acc0 = fmaf(readlane_f(w0, j + 3), bf_lo(u3), acc0);
            acc1 = fmaf(readlane_f(w1, j + 3), bf_hi(u3), acc1);
            acc0 = fmaf(readlane_f(w0, j + 4), bf_lo(u4), acc0);
            acc1 = fmaf(readlane_f(w1, j + 4), bf_hi(u4), acc1);
            acc0 = fmaf(readlane_f(w0, j + 5), bf_lo(u5), acc0);
            acc1 = fmaf(readlane_f(w1, j + 5), bf_hi(u5), acc1);
            acc0 = fmaf(readlane_f(w0, j + 6), bf_lo(u6), acc0);
            acc1 = fmaf(readlane_f(w1, j + 6), bf_hi(u6), acc1);
            acc0 = fmaf(readlane_f(w0, j + 7), bf_lo(u7), acc0);
            acc1 = fmaf(readlane_f(w1, j + 7), bf_hi(u7), acc1);
        }
        for (; j < cnt; ++j) {
            int   sj = __builtin_amdgcn_readlane(s, j);
            float p = readlane_f(w0, j), q = readlane_f(w1, j);
            unsigned u = hpk[(size_t)sj * 64 + lane];
            acc0 = fmaf(p, bf_lo(u), acc0);
            acc1 = fmaf(q, bf_hi(u), acc1);
        }
    }
    float o0 = acc0 / (sum0 + 1e-16f) + bias[lane];
    float o1 = acc1 / (sum1 + 1e-16f) + bias[64 + lane];
    out1b[(size_t)node * 128 + lane]      = f2bf(fmaxf(o0, 0.f));
    out1b[(size_t)node * 128 + 64 + lane] = f2bf(fmaxf(o1, 0.f));
}

// ---------------------------------------------------------------- agg layer2: no-max, bf16 gather, no relu
__global__ void agg_layer2(const unsigned short* __restrict__ hb, const float* __restrict__ asrc,
                           const float* __restrict__ adst, const int* __restrict__ offs,
                           const int* __restrict__ csr, const float* __restrict__ bias,
                           float* __restrict__ out, int N) {
    int node = (blockIdx.x * blockDim.x + threadIdx.x) >> 6;
    int lane = threadIdx.x & 63;
    if (node >= N) return;
    int off = offs[node], end = offs[node + 1];
    float ad = adst[node];
    float wself = __expf(fminf(LEAKY(asrc[node] + ad), 60.f));
    float sum = wself;
    float acc = wself * __uint_as_float((unsigned)hb[(size_t)node * 64 + lane] << 16);

    for (int chunk = off; chunk < end; chunk += 64) {
        int e = chunk + lane;
        int s = 0;
        float w = 0.f;
        if (e < end) {
            s = csr[e];
            w = __expf(fminf(LEAKY(asrc[s] + ad), 60.f));
        }
        float t = w;
#pragma unroll
        for (int o = 32; o > 0; o >>= 1) t += __shfl_xor(t, o);
        sum += t;

        int cnt = min(64, end - chunk);
        int j = 0;
        for (; j + 8 <= cnt; j += 8) {
            int sj0 = __builtin_amdgcn_readlane(s, j);
            int sj1 = __builtin_amdgcn_readlane(s, j + 1);
            int sj2 = __builtin_amdgcn_readlane(s, j + 2);
            int sj3 = __builtin_amdgcn_readlane(s, j + 3);
            int sj4 = __builtin_amdgcn_readlane(s, j + 4);
            int sj5 = __builtin_amdgcn_readlane(s, j + 5);
            int sj6 = __builtin_amdgcn_readlane(s, j + 6);
            int sj7 = __builtin_amdgcn_readlane(s, j + 7);
            float v0 = __uint_as_float((unsigned)hb[(size_t)sj0 * 64 + lane] << 16);
            float v1 = __uint_as_float((unsigned)hb[(size_t)sj1 * 64 + lane] << 16);
            float v2 = __uint_as_float((unsigned)hb[(size_t)sj2 * 64 + lane] << 16);
            float v3 = __uint_as_float((unsigned)hb[(size_t)sj3 * 64 + lane] << 16);
            float v4 = __uint_as_float((unsigned)hb[(size_t)sj4 * 64 + lane] << 16);
            float v5 = __uint_as_float((unsigned)hb[(size_t)sj5 * 64 + lane] << 16);
            float v6 = __uint_as_float((unsigned)hb[(size_t)sj6 * 64 + lane] << 16);
            float v7 = __uint_as_float((unsigned)hb[(size_t)sj7 * 64 + lane] << 16);
            acc = fmaf(readlane_f(w, j),     v0, acc);
            acc = fmaf(readlane_f(w, j + 1), v1, acc);
            acc = fmaf(readlane_f(w, j + 2), v2, acc);
            acc = fmaf(readlane_f(w, j + 3), v3, acc);
            acc = fmaf(readlane_f(w, j + 4), v4, acc);
            acc = fmaf(readlane_f(w, j + 5), v5, acc);
            acc = fmaf(readlane_f(w, j + 6), v6, acc);
            acc = fmaf(readlane_f(w, j + 7), v7, acc);
        }
        for (; j < cnt; ++j) {
            int   sj = __builtin_amdgcn_readlane(s, j);
            float p = readlane_f(w, j);
            acc = fmaf(p, __uint_as_float((unsigned)hb[(size_t)sj * 64 + lane] << 16), acc);
        }
    }
    out[(size_t)node * 64 + lane] = acc / (sum + 1e-16f) + bias[lane];
}

// ---------------------------------------------------------------- host
extern "C" void kernel_launch(void* const* d_in, const int* in_sizes, int n_in,
                              void* d_out, int out_size, void* d_ws, size_t ws_size,
                              hipStream_t stream) {
    const float* x        = (const float*)d_in[0];
    const int* ei         = (const int*)d_in[1];
    const float* W1       = (const float*)d_in[2];
    const float* att_src1 = (const float*)d_in[3];
    const float* att_dst1 = (const float*)d_in[4];
    const float* bias1    = (const float*)d_in[5];
    const float* W2       = (const float*)d_in[6];
    const float* att_src2 = (const float*)d_in[7];
    const float* att_dst2 = (const float*)d_in[8];
    const float* bias2    = (const float*)d_in[9];

    const int N = in_sizes[0] / 128;  // 100000
    const int E = in_sizes[1] / 2;    // 1600000

    char* base = (char*)d_ws;
    size_t off = 0;
    auto alloc = [&](size_t bytes) {
        char* p = base + off;
        off = (off + bytes + 255) & ~(size_t)255;
        return p;
    };
    int*      bcnt    = (int*)alloc((size_t)NBUCK * BPAD * 4);
    int*      bcur    = (int*)alloc((size_t)NBUCK * BPAD * 4);
    int*      bstart  = (int*)alloc((size_t)(NBUCK + 1) * 4);
    int*      offsets = (int*)alloc((size_t)(N + 1) * 4);
    int*      csr     = (int*)alloc((size_t)E * 4);
    int2*     ebuf    = (int2*)alloc((size_t)E * 8);
    unsigned* hpk     = (unsigned*)alloc((size_t)N * 64 * 4);        // packed bf16 pairs L1
    unsigned short* hb    = (unsigned short*)alloc((size_t)N * 64 * 2);  // bf16 L2 features
    unsigned short* out1b = (unsigned short*)alloc((size_t)N * 128 * 2); // L1 output, bf16
    float*    asrc1   = (float*)alloc((size_t)N * 2 * 4);
    float*    adst1   = (float*)alloc((size_t)N * 2 * 4);
    float*    asrc2   = (float*)alloc((size_t)N * 4);
    float*    adst2   = (float*)alloc((size_t)N * 4);

    const int mblocks64 = (N + 63) / 64;              // 1563
    const int nwave_blocks = (N + 3) / 4;
    const int histBlocks = (E + 4095) / 4096;         // 391
    const int p1Blocks = (E + 4095) / 4096;           // 391
    const int nbuckets = (N + (1 << BSH) - 1) >> BSH; // 98

    // --- CSR prefix ---
    hipMemsetAsync(bcnt, 0, (size_t)NBUCK * BPAD * 4, stream);
    hist_bucket<<<histBlocks, 256, 0, stream>>>(ei, E, bcnt, histBlocks);
    scan_bucket<<<1, 64, 0, stream>>>(bcnt, bcur, bstart, offsets, N);

    // --- K1: MFMA GEMM1+epilogue || pass1 edge binning ---
    fused_gemm1_pass1<<<p1Blocks + mblocks64, 256, 0, stream>>>(
        x, W1, N, att_src1, att_dst1, hpk, asrc1, adst1, ei, E, bcur, ebuf, p1Blocks);

    // --- K2: per-bucket offsets + localized scatter ---
    pass2_build<<<nbuckets, 256, 0, stream>>>(ebuf, bstart, offsets, csr, N);

    // --- layer 1 aggregate (writes bf16) ---
    agg_layer1<<<nwave_blocks, 256, 0, stream>>>(hpk, asrc1, adst1, offsets, csr, bias1, out1b, N);

    // --- K3: MFMA GEMM2+epilogue ---
    gemm2_epi<<<mblocks64, 256, 0, stream>>>(out1b, W2, N, att_src2, att_dst2, hb, asrc2, adst2);

    // --- layer 2 aggregate ---
    agg_layer2<<<nwave_blocks, 256, 0, stream>>>(hb, asrc2, adst2, offsets, csr, bias2,
                                                 (float*)d_out, N);
}

// Round 14
// 230.661 us; speedup vs baseline: 1.0601x; 1.0601x over previous
//
#include <hip/hip_runtime.h>
#include <hip/hip_bf16.h>
#include <cstdint>
#include <cstddef>

#define LEAKY(x) ((x) > 0.f ? (x) : 0.2f * (x))

#define NBUCK 256          // buckets of 512 nodes (N=100000 -> 196 used)
#define BSH   9            // bucket shift
#define BPAD  16           // pad counters one 64B line apart
#define WPAD  136          // LDS W row pad (272B stride -> near-conflict-free frag reads)

typedef float        f32x4  __attribute__((ext_vector_type(4)));
typedef unsigned int u32x4  __attribute__((ext_vector_type(4)));
typedef short        bf16x8 __attribute__((ext_vector_type(8)));

__device__ __forceinline__ float readlane_f(float v, int l) {
    return __int_as_float(__builtin_amdgcn_readlane(__float_as_int(v), l));
}
// round-to-nearest-even fp32 -> bf16 bits
__device__ __forceinline__ unsigned short f2bf(float f) {
    unsigned x = __float_as_uint(f);
    return (unsigned short)((x + 0x7fffu + ((x >> 16) & 1u)) >> 16);
}
__device__ __forceinline__ float bf_lo(unsigned u) { return __uint_as_float(u << 16); }
__device__ __forceinline__ float bf_hi(unsigned u) { return __uint_as_float(u & 0xffff0000u); }

__device__ __forceinline__ bf16x8 as_bf16x8(u32x4 u) {
    union { u32x4 u4; bf16x8 b; } cv;
    cv.u4 = u;
    return cv.b;
}

// ---------------------------------------------------------------- bucket histogram
__global__ void hist_bucket(const int* __restrict__ ei, int E, int* __restrict__ bcnt,
                            int nblocks) {
    __shared__ int bl[NBUCK];
    for (int i = threadIdx.x; i < NBUCK; i += 256) bl[i] = 0;
    __syncthreads();
    const int stride = nblocks * 256;
    for (int e = blockIdx.x * 256 + threadIdx.x; e < E; e += stride)
        atomicAdd(&bl[ei[E + e] >> BSH], 1);
    __syncthreads();
    for (int i = threadIdx.x; i < NBUCK; i += 256) {
        int c = bl[i];
        if (c) atomicAdd(&bcnt[i * BPAD], c);
    }
}

// bucket exclusive scan (tiny)
__global__ void scan_bucket(const int* __restrict__ bcnt, int* __restrict__ bcur,
                            int* __restrict__ bstart, int* __restrict__ offsets, int n) {
    if (threadIdx.x == 0 && blockIdx.x == 0) {
        int run = 0;
        for (int b = 0; b < NBUCK; ++b) {
            int v = bcnt[b * BPAD];
            bcur[b * BPAD] = run;
            bstart[b] = run;
            run += v;
        }
        bstart[NBUCK] = run;
        offsets[n] = run;
    }
}

// ---------------------------------------------------------------- K1: pass1 (edge binning) || MFMA GEMM1 + epilogue
__global__ __launch_bounds__(256) void fused_gemm1_pass1(
    const float* __restrict__ x, const float* __restrict__ W1, int M,
    const float* __restrict__ att_src, const float* __restrict__ att_dst,
    unsigned* __restrict__ hpk, float* __restrict__ asrc, float* __restrict__ adst,
    const int* __restrict__ ei, int E, int* __restrict__ bcur, int2* __restrict__ ebuf,
    int p1Blocks) {
    const int tid = threadIdx.x;
    if ((int)blockIdx.x < p1Blocks) {
        __shared__ int bcnt_l[NBUCK];
        __shared__ int bbase_l[NBUCK];
        const int e0 = (int)blockIdx.x * 4096;
        const int ecnt = min(4096, E - e0);
        for (int i = tid; i < NBUCK; i += 256) bcnt_l[i] = 0;
        __syncthreads();
        for (int i = tid; i < ecnt; i += 256)
            atomicAdd(&bcnt_l[ei[E + e0 + i] >> BSH], 1);
        __syncthreads();
        if (tid < NBUCK) {
            int c = bcnt_l[tid];
            bbase_l[tid] = c ? atomicAdd(&bcur[tid * BPAD], c) : 0;
            bcnt_l[tid] = 0;
        }
        __syncthreads();
        for (int i = tid; i < ecnt; i += 256) {
            int s = ei[e0 + i];
            int d = ei[E + e0 + i];
            int b = d >> BSH;
            int l = atomicAdd(&bcnt_l[b], 1);
            ebuf[bbase_l[b] + l] = make_int2(s, d);
        }
    } else {
        __shared__ unsigned short Wt[128][WPAD];   // [col][k], bf16
        for (int i = tid; i < 128 * 128; i += 256) {
            int k = i >> 7, c = i & 127;
            Wt[c][k] = f2bf(W1[i]);
        }
        __syncthreads();
        const int gb = (int)blockIdx.x - p1Blocks;
        const int lane = tid & 63;
        const int li = lane & 15, g = lane >> 4;
        const int row0 = gb * 64 + (tid >> 6) * 16;
        const int arow = min(row0 + li, M - 1);
        f32x4 acc[8];
#pragma unroll
        for (int ct = 0; ct < 8; ++ct) acc[ct] = (f32x4)(0.f);
        const float* ap = x + (size_t)arow * 128 + g * 8;
#pragma unroll
        for (int ks = 0; ks < 4; ++ks) {
            float4 a0 = *(const float4*)(ap + ks * 32);
            float4 a1 = *(const float4*)(ap + ks * 32 + 4);
            u32x4 af;
            af.x = (unsigned)f2bf(a0.x) | ((unsigned)f2bf(a0.y) << 16);
            af.y = (unsigned)f2bf(a0.z) | ((unsigned)f2bf(a0.w) << 16);
            af.z = (unsigned)f2bf(a1.x) | ((unsigned)f2bf(a1.y) << 16);
            af.w = (unsigned)f2bf(a1.z) | ((unsigned)f2bf(a1.w) << 16);
            bf16x8 av = as_bf16x8(af);
#pragma unroll
            for (int ct = 0; ct < 8; ++ct) {
                bf16x8 bv = *(const bf16x8*)&Wt[ct * 16 + li][ks * 32 + g * 8];
                acc[ct] = __builtin_amdgcn_mfma_f32_16x16x32_bf16(av, bv, acc[ct], 0, 0, 0);
            }
        }
        // epilogue: scores + bf16 pack. head0 = cols 0..63 (ct 0..3), head1 = 64..127.
        float asv[8], adv[8];
#pragma unroll
        for (int ct = 0; ct < 8; ++ct) {
            asv[ct] = att_src[ct * 16 + li];
            adv[ct] = att_dst[ct * 16 + li];
        }
#pragma unroll
        for (int reg = 0; reg < 4; ++reg) {
            int r = row0 + g * 4 + reg;
            float ps0 = 0.f, pd0 = 0.f, ps1 = 0.f, pd1 = 0.f;
#pragma unroll
            for (int ct = 0; ct < 4; ++ct) {
                ps0 = fmaf(acc[ct][reg], asv[ct], ps0);
                pd0 = fmaf(acc[ct][reg], adv[ct], pd0);
                ps1 = fmaf(acc[ct + 4][reg], asv[ct + 4], ps1);
                pd1 = fmaf(acc[ct + 4][reg], adv[ct + 4], pd1);
            }
#pragma unroll
            for (int m = 8; m > 0; m >>= 1) {
                ps0 += __shfl_xor(ps0, m);
                pd0 += __shfl_xor(pd0, m);
                ps1 += __shfl_xor(ps1, m);
                pd1 += __shfl_xor(pd1, m);
            }
            if (r < M) {
                if (li == 0) {
                    asrc[2 * r] = ps0; asrc[2 * r + 1] = ps1;
                    adst[2 * r] = pd0; adst[2 * r + 1] = pd1;
                }
#pragma unroll
                for (int ct = 0; ct < 4; ++ct)
                    hpk[(size_t)r * 64 + ct * 16 + li] =
                        (unsigned)f2bf(acc[ct][reg]) | ((unsigned)f2bf(acc[ct + 4][reg]) << 16);
            }
        }
    }
}

// ---------------------------------------------------------------- K2: per-bucket offsets + localized scatter
// one block per 512-node bucket; LDS cursor; csr writes confined to ~private window.
__global__ __launch_bounds__(256) void pass2_build(
    const int2* __restrict__ ebuf, const int* __restrict__ bstart, int* __restrict__ offsets,
    int* __restrict__ csr, int N) {
    __shared__ int lcur[1 << BSH];
    __shared__ int ssum[256];
    const int b = blockIdx.x;
    const int dbase = b << BSH;
    const int tid = threadIdx.x;
    for (int i = tid; i < (1 << BSH); i += 256) lcur[i] = 0;
    __syncthreads();
    const int es = bstart[b], ee = bstart[b + 1];
    for (int i = es + tid; i < ee; i += 256)
        atomicAdd(&lcur[ebuf[i].y - dbase], 1);
    __syncthreads();
    // local exclusive scan of 512 counts (2 per thread)
    const int base_ = tid * 2;
    int v0 = lcur[base_], v1 = lcur[base_ + 1];
    ssum[tid] = v0 + v1;
    __syncthreads();
    for (int o = 1; o < 256; o <<= 1) {
        int add = (tid >= o) ? ssum[tid - o] : 0;
        __syncthreads();
        ssum[tid] += add;
        __syncthreads();
    }
    int excl = (tid ? ssum[tid - 1] : 0) + bstart[b];
    int c0 = excl, c1 = c0 + v0;
    lcur[base_] = c0; lcur[base_ + 1] = c1;
    int idx = dbase + base_;
    if (idx < N)     offsets[idx] = c0;
    if (idx + 1 < N) offsets[idx + 1] = c1;
    __syncthreads();
    for (int i = es + tid; i < ee; i += 256) {
        int2 p = ebuf[i];
        int pos = atomicAdd(&lcur[p.y - dbase], 1);
        csr[pos] = p.x;
    }
}

// ---------------------------------------------------------------- K3: MFMA GEMM2 + epilogue
__global__ __launch_bounds__(256) void gemm2_epi(
    const unsigned short* __restrict__ A, const float* __restrict__ W2, int M,
    const float* __restrict__ att_src, const float* __restrict__ att_dst,
    unsigned short* __restrict__ hb, float* __restrict__ asrc, float* __restrict__ adst) {
    __shared__ unsigned short Wt[64][WPAD];
    const int tid = threadIdx.x;
    for (int i = tid; i < 128 * 64; i += 256) {
        int k = i >> 6, c = i & 63;
        Wt[c][k] = f2bf(W2[i]);
    }
    __syncthreads();
    const int lane = tid & 63;
    const int li = lane & 15, g = lane >> 4;
    const int row0 = blockIdx.x * 64 + (tid >> 6) * 16;
    const int arow = min(row0 + li, M - 1);
    f32x4 acc[4];
#pragma unroll
    for (int ct = 0; ct < 4; ++ct) acc[ct] = (f32x4)(0.f);
    const unsigned short* ap = A + (size_t)arow * 128 + g * 8;
#pragma unroll
    for (int ks = 0; ks < 4; ++ks) {
        bf16x8 av = *(const bf16x8*)(ap + ks * 32);
#pragma unroll
        for (int ct = 0; ct < 4; ++ct) {
            bf16x8 bv = *(const bf16x8*)&Wt[ct * 16 + li][ks * 32 + g * 8];
            acc[ct] = __builtin_amdgcn_mfma_f32_16x16x32_bf16(av, bv, acc[ct], 0, 0, 0);
        }
    }
    float asv[4], adv[4];
#pragma unroll
    for (int ct = 0; ct < 4; ++ct) {
        asv[ct] = att_src[ct * 16 + li];
        adv[ct] = att_dst[ct * 16 + li];
    }
#pragma unroll
    for (int reg = 0; reg < 4; ++reg) {
        int r = row0 + g * 4 + reg;
        float ps = 0.f, pd = 0.f;
#pragma unroll
        for (int ct = 0; ct < 4; ++ct) {
            ps = fmaf(acc[ct][reg], asv[ct], ps);
            pd = fmaf(acc[ct][reg], adv[ct], pd);
        }
#pragma unroll
        for (int m = 8; m > 0; m >>= 1) {
            ps += __shfl_xor(ps, m);
            pd += __shfl_xor(pd, m);
        }
        if (r < M) {
            if (li == 0) { asrc[r] = ps; adst[r] = pd; }
#pragma unroll
            for (int ct = 0; ct < 4; ++ct)
                hb[(size_t)r * 64 + ct * 16 + li] = f2bf(acc[ct][reg]);
        }
    }
}

// ---------------------------------------------------------------- agg layer1: no-max softmax + aggregate, bf16 out
__global__ void agg_layer1(const unsigned* __restrict__ hpk, const float* __restrict__ asrc,
                           const float* __restrict__ adst, const int* __restrict__ offs,
                           const int* __restrict__ csr, const float* __restrict__ bias,
                           unsigned short* __restrict__ out1b, int N) {
    int node = (blockIdx.x * blockDim.x + threadIdx.x) >> 6;
    int lane = threadIdx.x & 63;
    if (node >= N) return;
    int off = offs[node], end = offs[node + 1];
    float ad0 = adst[2 * node], ad1 = adst[2 * node + 1];
    float ws0 = __expf(fminf(LEAKY(asrc[2 * node] + ad0), 60.f));
    float ws1 = __expf(fminf(LEAKY(asrc[2 * node + 1] + ad1), 60.f));
    float sum0 = ws0, sum1 = ws1;
    float acc0, acc1;
    {
        unsigned u = hpk[(size_t)node * 64 + lane];
        acc0 = ws0 * bf_lo(u);
        acc1 = ws1 * bf_hi(u);
    }
    for (int chunk = off; chunk < end; chunk += 64) {
        int e = chunk + lane;
        int s = 0;
        float w0 = 0.f, w1 = 0.f;
        if (e < end) {
            s = csr[e];
            float2 as = *(const float2*)&asrc[2 * s];
            w0 = __expf(fminf(LEAKY(as.x + ad0), 60.f));
            w1 = __expf(fminf(LEAKY(as.y + ad1), 60.f));
        }
        float t0 = w0, t1 = w1;
#pragma unroll
        for (int o = 32; o > 0; o >>= 1) {
            t0 += __shfl_xor(t0, o);
            t1 += __shfl_xor(t1, o);
        }
        sum0 += t0; sum1 += t1;

        int cnt = min(64, end - chunk);
        int j = 0;
        for (; j + 4 <= cnt; j += 4) {
            int   sj0 = __builtin_amdgcn_readlane(s, j);
            int   sj1 = __builtin_amdgcn_readlane(s, j + 1);
            int   sj2 = __builtin_amdgcn_readlane(s, j + 2);
            int   sj3 = __builtin_amdgcn_readlane(s, j + 3);
            float p0 = readlane_f(w0, j),     q0 = readlane_f(w1, j);
            float p1 = readlane_f(w0, j + 1), q1 = readlane_f(w1, j + 1);
            float p2 = readlane_f(w0, j + 2), q2 = readlane_f(w1, j + 2);
            float p3 = readlane_f(w0, j + 3), q3 = readlane_f(w1, j + 3);
            unsigned u0 = hpk[(size_t)sj0 * 64 + lane];
            unsigned u1 = hpk[(size_t)sj1 * 64 + lane];
            unsigned u2 = hpk[(size_t)sj2 * 64 + lane];
            unsigned u3 = hpk[(size_t)sj3 * 64 + lane];
            acc0 = fmaf(p0, bf_lo(u0), acc0); acc1 = fmaf(q0, bf_hi(u0), acc1);
            acc0 = fmaf(p1, bf_lo(u1), acc0); acc1 = fmaf(q1, bf_hi(u1), acc1);
            acc0 = fmaf(p2, bf_lo(u2), acc0); acc1 = fmaf(q2, bf_hi(u2), acc1);
            acc0 = fmaf(p3, bf_lo(u3), acc0); acc1 = fmaf(q3, bf_hi(u3), acc1);
        }
        for (; j < cnt; ++j) {
            int   sj = __builtin_amdgcn_readlane(s, j);
            float p = readlane_f(w0, j), q = readlane_f(w1, j);
            unsigned u = hpk[(size_t)sj * 64 + lane];
            acc0 = fmaf(p, bf_lo(u), acc0);
            acc1 = fmaf(q, bf_hi(u), acc1);
        }
    }
    float o0 = acc0 / (sum0 + 1e-16f) + bias[lane];
    float o1 = acc1 / (sum1 + 1e-16f) + bias[64 + lane];
    out1b[(size_t)node * 128 + lane]      = f2bf(fmaxf(o0, 0.f));
    out1b[(size_t)node * 128 + 64 + lane] = f2bf(fmaxf(o1, 0.f));
}

// ---------------------------------------------------------------- agg layer2: no-max, bf16 gather, no relu
__global__ void agg_layer2(const unsigned short* __restrict__ hb, const float* __restrict__ asrc,
                           const float* __restrict__ adst, const int* __restrict__ offs,
                           const int* __restrict__ csr, const float* __restrict__ bias,
                           float* __restrict__ out, int N) {
    int node = (blockIdx.x * blockDim.x + threadIdx.x) >> 6;
    int lane = threadIdx.x & 63;
    if (node >= N) return;
    int off = offs[node], end = offs[node + 1];
    float ad = adst[node];
    float wself = __expf(fminf(LEAKY(asrc[node] + ad), 60.f));
    float sum = wself;
    float acc = wself * __uint_as_float((unsigned)hb[(size_t)node * 64 + lane] << 16);

    for (int chunk = off; chunk < end; chunk += 64) {
        int e = chunk + lane;
        int s = 0;
        float w = 0.f;
        if (e < end) {
            s = csr[e];
            w = __expf(fminf(LEAKY(asrc[s] + ad), 60.f));
        }
        float t = w;
#pragma unroll
        for (int o = 32; o > 0; o >>= 1) t += __shfl_xor(t, o);
        sum += t;

        int cnt = min(64, end - chunk);
        int j = 0;
        for (; j + 4 <= cnt; j += 4) {
            int   sj0 = __builtin_amdgcn_readlane(s, j);
            int   sj1 = __builtin_amdgcn_readlane(s, j + 1);
            int   sj2 = __builtin_amdgcn_readlane(s, j + 2);
            int   sj3 = __builtin_amdgcn_readlane(s, j + 3);
            float p0 = readlane_f(w, j);
            float p1 = readlane_f(w, j + 1);
            float p2 = readlane_f(w, j + 2);
            float p3 = readlane_f(w, j + 3);
            float v0 = __uint_as_float((unsigned)hb[(size_t)sj0 * 64 + lane] << 16);
            float v1 = __uint_as_float((unsigned)hb[(size_t)sj1 * 64 + lane] << 16);
            float v2 = __uint_as_float((unsigned)hb[(size_t)sj2 * 64 + lane] << 16);
            float v3 = __uint_as_float((unsigned)hb[(size_t)sj3 * 64 + lane] << 16);
            acc = fmaf(p0, v0, acc);
            acc = fmaf(p1, v1, acc);
            acc = fmaf(p2, v2, acc);
            acc = fmaf(p3, v3, acc);
        }
        for (; j < cnt; ++j) {
            int   sj = __builtin_amdgcn_readlane(s, j);
            float p = readlane_f(w, j);
            acc = fmaf(p, __uint_as_float((unsigned)hb[(size_t)sj * 64 + lane] << 16), acc);
        }
    }
    out[(size_t)node * 64 + lane] = acc / (sum + 1e-16f) + bias[lane];
}

// ---------------------------------------------------------------- host
extern "C" void kernel_launch(void* const* d_in, const int* in_sizes, int n_in,
                              void* d_out, int out_size, void* d_ws, size_t ws_size,
                              hipStream_t stream) {
    const float* x        = (const float*)d_in[0];
    const int* ei         = (const int*)d_in[1];
    const float* W1       = (const float*)d_in[2];
    const float* att_src1 = (const float*)d_in[3];
    const float* att_dst1 = (const float*)d_in[4];
    const float* bias1    = (const float*)d_in[5];
    const float* W2       = (const float*)d_in[6];
    const float* att_src2 = (const float*)d_in[7];
    const float* att_dst2 = (const float*)d_in[8];
    const float* bias2    = (const float*)d_in[9];

    const int N = in_sizes[0] / 128;  // 100000
    const int E = in_sizes[1] / 2;    // 1600000

    char* base = (char*)d_ws;
    size_t off = 0;
    auto alloc = [&](size_t bytes) {
        char* p = base + off;
        off = (off + bytes + 255) & ~(size_t)255;
        return p;
    };
    int*      bcnt    = (int*)alloc((size_t)NBUCK * BPAD * 4);
    int*      bcur    = (int*)alloc((size_t)NBUCK * BPAD * 4);
    int*      bstart  = (int*)alloc((size_t)(NBUCK + 1) * 4);
    int*      offsets = (int*)alloc((size_t)(N + 1) * 4);
    int*      csr     = (int*)alloc((size_t)E * 4);
    int2*     ebuf    = (int2*)alloc((size_t)E * 8);
    unsigned* hpk     = (unsigned*)alloc((size_t)N * 64 * 4);        // packed bf16 pairs L1
    unsigned short* hb    = (unsigned short*)alloc((size_t)N * 64 * 2);  // bf16 L2 features
    unsigned short* out1b = (unsigned short*)alloc((size_t)N * 128 * 2); // L1 output, bf16
    float*    asrc1   = (float*)alloc((size_t)N * 2 * 4);
    float*    adst1   = (float*)alloc((size_t)N * 2 * 4);
    float*    asrc2   = (float*)alloc((size_t)N * 4);
    float*    adst2   = (float*)alloc((size_t)N * 4);

    const int mblocks64 = (N + 63) / 64;              // 1563
    const int nwave_blocks = (N + 3) / 4;
    const int histBlocks = (E + 4095) / 4096;         // 391
    const int p1Blocks = (E + 4095) / 4096;           // 391
    const int nbuckets = (N + (1 << BSH) - 1) >> BSH; // 196

    // --- CSR prefix ---
    hipMemsetAsync(bcnt, 0, (size_t)NBUCK * BPAD * 4, stream);
    hist_bucket<<<histBlocks, 256, 0, stream>>>(ei, E, bcnt, histBlocks);
    scan_bucket<<<1, 64, 0, stream>>>(bcnt, bcur, bstart, offsets, N);

    // --- K1: MFMA GEMM1+epilogue || pass1 edge binning ---
    fused_gemm1_pass1<<<p1Blocks + mblocks64, 256, 0, stream>>>(
        x, W1, N, att_src1, att_dst1, hpk, asrc1, adst1, ei, E, bcur, ebuf, p1Blocks);

    // --- K2: per-bucket offsets + localized scatter ---
    pass2_build<<<nbuckets, 256, 0, stream>>>(ebuf, bstart, offsets, csr, N);

    // --- layer 1 aggregate (writes bf16) ---
    agg_layer1<<<nwave_blocks, 256, 0, stream>>>(hpk, asrc1, adst1, offsets, csr, bias1, out1b, N);

    // --- K3: MFMA GEMM2+epilogue ---
    gemm2_epi<<<mblocks64, 256, 0, stream>>>(out1b, W2, N, att_src2, att_dst2, hb, asrc2, adst2);

    // --- layer 2 aggregate ---
    agg_layer2<<<nwave_blocks, 256, 0, stream>>>(hb, asrc2, adst2, offsets, csr, bias2,
                                                 (float*)d_out, N);
}

// Round 15
// 217.818 us; speedup vs baseline: 1.1226x; 1.0590x over previous
//
#include <hip/hip_runtime.h>
#include <hip/hip_bf16.h>
#include <cstdint>
#include <cstddef>

#define LEAKY(x) ((x) > 0.f ? (x) : 0.2f * (x))

#define NBUCK 256          // bucket array size (196 used: 512-node buckets)
#define BSH   9            // bucket shift
#define BPAD  16           // pad counters one 64B line apart
#define CAP   16384        // fixed edge capacity per bucket (mean 8163, 46-sigma margin)
#define WPAD  136          // LDS W row pad

typedef float        f32x4  __attribute__((ext_vector_type(4)));
typedef unsigned int u32x4  __attribute__((ext_vector_type(4)));
typedef short        bf16x8 __attribute__((ext_vector_type(8)));

__device__ __forceinline__ float readlane_f(float v, int l) {
    return __int_as_float(__builtin_amdgcn_readlane(__float_as_int(v), l));
}
__device__ __forceinline__ unsigned short f2bf(float f) {
    unsigned x = __float_as_uint(f);
    return (unsigned short)((x + 0x7fffu + ((x >> 16) & 1u)) >> 16);
}
__device__ __forceinline__ float bf_lo(unsigned u) { return __uint_as_float(u << 16); }
__device__ __forceinline__ float bf_hi(unsigned u) { return __uint_as_float(u & 0xffff0000u); }

__device__ __forceinline__ bf16x8 as_bf16x8(u32x4 u) {
    union { u32x4 u4; bf16x8 b; } cv;
    cv.u4 = u;
    return cv.b;
}

// ---------------------------------------------------------------- K1: pass1 (fixed-cap binning) || MFMA GEMM1 + epilogue
__global__ __launch_bounds__(256) void fused_gemm1_pass1(
    const float* __restrict__ x, const float* __restrict__ W1, int M,
    const float* __restrict__ att_src, const float* __restrict__ att_dst,
    unsigned* __restrict__ hpk, float* __restrict__ asrc, float* __restrict__ adst,
    const int* __restrict__ ei, int E, int* __restrict__ bcur, int2* __restrict__ ebuf,
    int2* __restrict__ obuf, int* __restrict__ ocnt, int p1Blocks) {
    const int tid = threadIdx.x;
    if ((int)blockIdx.x < p1Blocks) {
        __shared__ int bcnt_l[NBUCK];
        __shared__ int bbase_l[NBUCK];
        const int e0 = (int)blockIdx.x * 4096;
        const int ecnt = min(4096, E - e0);
        for (int i = tid; i < NBUCK; i += 256) bcnt_l[i] = 0;
        __syncthreads();
        for (int i = tid; i < ecnt; i += 256)
            atomicAdd(&bcnt_l[ei[E + e0 + i] >> BSH], 1);
        __syncthreads();
        if (tid < NBUCK) {
            int c = bcnt_l[tid];
            bbase_l[tid] = c ? atomicAdd(&bcur[tid * BPAD], c) : 0;
            bcnt_l[tid] = 0;
        }
        __syncthreads();
        for (int i = tid; i < ecnt; i += 256) {
            int s = ei[e0 + i];
            int d = ei[E + e0 + i];
            int b = d >> BSH;
            int l = atomicAdd(&bcnt_l[b], 1);
            int g = bbase_l[b] + l;
            if (g < CAP) {
                ebuf[(size_t)b * CAP + g] = make_int2(s, d);
            } else {
                int oi = atomicAdd(ocnt, 1);
                obuf[oi & 65535] = make_int2(s, d);   // 64K guard (never hit for this graph)
            }
        }
    } else {
        __shared__ unsigned short Wt[128][WPAD];   // [col][k], bf16
        for (int i = tid; i < 128 * 128; i += 256) {
            int k = i >> 7, c = i & 127;
            Wt[c][k] = f2bf(W1[i]);
        }
        __syncthreads();
        const int gb = (int)blockIdx.x - p1Blocks;
        const int lane = tid & 63;
        const int li = lane & 15, g = lane >> 4;
        const int row0 = gb * 64 + (tid >> 6) * 16;
        const int arow = min(row0 + li, M - 1);
        f32x4 acc[8];
#pragma unroll
        for (int ct = 0; ct < 8; ++ct) acc[ct] = (f32x4)(0.f);
        const float* ap = x + (size_t)arow * 128 + g * 8;
#pragma unroll
        for (int ks = 0; ks < 4; ++ks) {
            float4 a0 = *(const float4*)(ap + ks * 32);
            float4 a1 = *(const float4*)(ap + ks * 32 + 4);
            u32x4 af;
            af.x = (unsigned)f2bf(a0.x) | ((unsigned)f2bf(a0.y) << 16);
            af.y = (unsigned)f2bf(a0.z) | ((unsigned)f2bf(a0.w) << 16);
            af.z = (unsigned)f2bf(a1.x) | ((unsigned)f2bf(a1.y) << 16);
            af.w = (unsigned)f2bf(a1.z) | ((unsigned)f2bf(a1.w) << 16);
            bf16x8 av = as_bf16x8(af);
#pragma unroll
            for (int ct = 0; ct < 8; ++ct) {
                bf16x8 bv = *(const bf16x8*)&Wt[ct * 16 + li][ks * 32 + g * 8];
                acc[ct] = __builtin_amdgcn_mfma_f32_16x16x32_bf16(av, bv, acc[ct], 0, 0, 0);
            }
        }
        float asv[8], adv[8];
#pragma unroll
        for (int ct = 0; ct < 8; ++ct) {
            asv[ct] = att_src[ct * 16 + li];
            adv[ct] = att_dst[ct * 16 + li];
        }
#pragma unroll
        for (int reg = 0; reg < 4; ++reg) {
            int r = row0 + g * 4 + reg;
            float ps0 = 0.f, pd0 = 0.f, ps1 = 0.f, pd1 = 0.f;
#pragma unroll
            for (int ct = 0; ct < 4; ++ct) {
                ps0 = fmaf(acc[ct][reg], asv[ct], ps0);
                pd0 = fmaf(acc[ct][reg], adv[ct], pd0);
                ps1 = fmaf(acc[ct + 4][reg], asv[ct + 4], ps1);
                pd1 = fmaf(acc[ct + 4][reg], adv[ct + 4], pd1);
            }
#pragma unroll
            for (int m = 8; m > 0; m >>= 1) {
                ps0 += __shfl_xor(ps0, m);
                pd0 += __shfl_xor(pd0, m);
                ps1 += __shfl_xor(ps1, m);
                pd1 += __shfl_xor(pd1, m);
            }
            if (r < M) {
                if (li == 0) {
                    asrc[2 * r] = ps0; asrc[2 * r + 1] = ps1;
                    adst[2 * r] = pd0; adst[2 * r + 1] = pd1;
                }
#pragma unroll
                for (int ct = 0; ct < 4; ++ct)
                    hpk[(size_t)r * 64 + ct * 16 + li] =
                        (unsigned)f2bf(acc[ct][reg]) | ((unsigned)f2bf(acc[ct + 4][reg]) << 16);
            }
        }
    }
}

// ---------------------------------------------------------------- K2: per-bucket offsets + localized scatter
// One block per bucket. Global csr offset derived from true bucket counts (LDS prefix).
__global__ __launch_bounds__(256) void pass2_build(
    const int2* __restrict__ ebuf, const int* __restrict__ bcur,
    const int2* __restrict__ obuf, const int* __restrict__ ocnt,
    int* __restrict__ offsets, int* __restrict__ csr, int N, int nbuckets) {
    __shared__ int lcur[1 << BSH];
    __shared__ int ssum[256];
    __shared__ int cnts[NBUCK];
    __shared__ int prefix_s;
    const int b = blockIdx.x;
    const int dbase = b << BSH;
    const int tid = threadIdx.x;
    if (tid < NBUCK) cnts[tid] = (tid < nbuckets) ? bcur[tid * BPAD] : 0;
    for (int i = tid; i < (1 << BSH); i += 256) lcur[i] = 0;
    __syncthreads();
    if (tid == 0) {
        int p = 0;
        for (int i = 0; i < b; ++i) p += cnts[i];
        prefix_s = p;
    }
    const int tc = cnts[b];
    const int ec = min(tc, CAP);
    const int2* eb = ebuf + (size_t)b * CAP;
    for (int i = tid; i < ec; i += 256)
        atomicAdd(&lcur[eb[i].y - dbase], 1);
    const int no = (tc > CAP) ? min(*ocnt, 65536) : 0;
    for (int i = tid; i < no; i += 256) {
        int2 p = obuf[i];
        if ((p.y >> BSH) == b) atomicAdd(&lcur[p.y - dbase], 1);
    }
    __syncthreads();
    // local exclusive scan of 512 counts (2/thread), base = prefix_s
    const int base_ = tid * 2;
    int v0 = lcur[base_], v1 = lcur[base_ + 1];
    ssum[tid] = v0 + v1;
    __syncthreads();
    for (int o = 1; o < 256; o <<= 1) {
        int add = (tid >= o) ? ssum[tid - o] : 0;
        __syncthreads();
        ssum[tid] += add;
        __syncthreads();
    }
    int excl = (tid ? ssum[tid - 1] : 0) + prefix_s;
    int c0 = excl, c1 = c0 + v0;
    lcur[base_] = c0; lcur[base_ + 1] = c1;
    int idx = dbase + base_;
    if (idx < N)     offsets[idx] = c0;
    if (idx + 1 < N) offsets[idx + 1] = c1;
    if (tid == 0 && b == nbuckets - 1) offsets[N] = prefix_s + tc;
    __syncthreads();
    for (int i = tid; i < ec; i += 256) {
        int2 p = eb[i];
        int pos = atomicAdd(&lcur[p.y - dbase], 1);
        csr[pos] = p.x;
    }
    for (int i = tid; i < no; i += 256) {
        int2 p = obuf[i];
        if ((p.y >> BSH) == b) {
            int pos = atomicAdd(&lcur[p.y - dbase], 1);
            csr[pos] = p.x;
        }
    }
}

// ---------------------------------------------------------------- K3: MFMA GEMM2 + epilogue
__global__ __launch_bounds__(256) void gemm2_epi(
    const unsigned short* __restrict__ A, const float* __restrict__ W2, int M,
    const float* __restrict__ att_src, const float* __restrict__ att_dst,
    unsigned short* __restrict__ hb, float* __restrict__ asrc, float* __restrict__ adst) {
    __shared__ unsigned short Wt[64][WPAD];
    const int tid = threadIdx.x;
    for (int i = tid; i < 128 * 64; i += 256) {
        int k = i >> 6, c = i & 63;
        Wt[c][k] = f2bf(W2[i]);
    }
    __syncthreads();
    const int lane = tid & 63;
    const int li = lane & 15, g = lane >> 4;
    const int row0 = blockIdx.x * 64 + (tid >> 6) * 16;
    const int arow = min(row0 + li, M - 1);
    f32x4 acc[4];
#pragma unroll
    for (int ct = 0; ct < 4; ++ct) acc[ct] = (f32x4)(0.f);
    const unsigned short* ap = A + (size_t)arow * 128 + g * 8;
#pragma unroll
    for (int ks = 0; ks < 4; ++ks) {
        bf16x8 av = *(const bf16x8*)(ap + ks * 32);
#pragma unroll
        for (int ct = 0; ct < 4; ++ct) {
            bf16x8 bv = *(const bf16x8*)&Wt[ct * 16 + li][ks * 32 + g * 8];
            acc[ct] = __builtin_amdgcn_mfma_f32_16x16x32_bf16(av, bv, acc[ct], 0, 0, 0);
        }
    }
    float asv[4], adv[4];
#pragma unroll
    for (int ct = 0; ct < 4; ++ct) {
        asv[ct] = att_src[ct * 16 + li];
        adv[ct] = att_dst[ct * 16 + li];
    }
#pragma unroll
    for (int reg = 0; reg < 4; ++reg) {
        int r = row0 + g * 4 + reg;
        float ps = 0.f, pd = 0.f;
#pragma unroll
        for (int ct = 0; ct < 4; ++ct) {
            ps = fmaf(acc[ct][reg], asv[ct], ps);
            pd = fmaf(acc[ct][reg], adv[ct], pd);
        }
#pragma unroll
        for (int m = 8; m > 0; m >>= 1) {
            ps += __shfl_xor(ps, m);
            pd += __shfl_xor(pd, m);
        }
        if (r < M) {
            if (li == 0) { asrc[r] = ps; adst[r] = pd; }
#pragma unroll
            for (int ct = 0; ct < 4; ++ct)
                hb[(size_t)r * 64 + ct * 16 + li] = f2bf(acc[ct][reg]);
        }
    }
}

// ---------------------------------------------------------------- agg layer1: no-max softmax + aggregate, bf16 out
__global__ void agg_layer1(const unsigned* __restrict__ hpk, const float* __restrict__ asrc,
                           const float* __restrict__ adst, const int* __restrict__ offs,
                           const int* __restrict__ csr, const float* __restrict__ bias,
                           unsigned short* __restrict__ out1b, int N) {
    int node = (blockIdx.x * blockDim.x + threadIdx.x) >> 6;
    int lane = threadIdx.x & 63;
    if (node >= N) return;
    int off = offs[node], end = offs[node + 1];
    float ad0 = adst[2 * node], ad1 = adst[2 * node + 1];
    float ws0 = __expf(fminf(LEAKY(asrc[2 * node] + ad0), 60.f));
    float ws1 = __expf(fminf(LEAKY(asrc[2 * node + 1] + ad1), 60.f));
    float sum0 = ws0, sum1 = ws1;
    float acc0, acc1;
    {
        unsigned u = hpk[(size_t)node * 64 + lane];
        acc0 = ws0 * bf_lo(u);
        acc1 = ws1 * bf_hi(u);
    }
    for (int chunk = off; chunk < end; chunk += 64) {
        int e = chunk + lane;
        int s = 0;
        float w0 = 0.f, w1 = 0.f;
        if (e < end) {
            s = __builtin_nontemporal_load(&csr[e]);
            float2 as = *(const float2*)&asrc[2 * s];
            w0 = __expf(fminf(LEAKY(as.x + ad0), 60.f));
            w1 = __expf(fminf(LEAKY(as.y + ad1), 60.f));
        }
        float t0 = w0, t1 = w1;
#pragma unroll
        for (int o = 32; o > 0; o >>= 1) {
            t0 += __shfl_xor(t0, o);
            t1 += __shfl_xor(t1, o);
        }
        sum0 += t0; sum1 += t1;

        int cnt = min(64, end - chunk);
        int j = 0;
        for (; j + 4 <= cnt; j += 4) {
            int   sj0 = __builtin_amdgcn_readlane(s, j);
            int   sj1 = __builtin_amdgcn_readlane(s, j + 1);
            int   sj2 = __builtin_amdgcn_readlane(s, j + 2);
            int   sj3 = __builtin_amdgcn_readlane(s, j + 3);
            float p0 = readlane_f(w0, j),     q0 = readlane_f(w1, j);
            float p1 = readlane_f(w0, j + 1), q1 = readlane_f(w1, j + 1);
            float p2 = readlane_f(w0, j + 2), q2 = readlane_f(w1, j + 2);
            float p3 = readlane_f(w0, j + 3), q3 = readlane_f(w1, j + 3);
            unsigned u0 = hpk[(size_t)sj0 * 64 + lane];
            unsigned u1 = hpk[(size_t)sj1 * 64 + lane];
            unsigned u2 = hpk[(size_t)sj2 * 64 + lane];
            unsigned u3 = hpk[(size_t)sj3 * 64 + lane];
            acc0 = fmaf(p0, bf_lo(u0), acc0); acc1 = fmaf(q0, bf_hi(u0), acc1);
            acc0 = fmaf(p1, bf_lo(u1), acc0); acc1 = fmaf(q1, bf_hi(u1), acc1);
            acc0 = fmaf(p2, bf_lo(u2), acc0); acc1 = fmaf(q2, bf_hi(u2), acc1);
            acc0 = fmaf(p3, bf_lo(u3), acc0); acc1 = fmaf(q3, bf_hi(u3), acc1);
        }
        for (; j < cnt; ++j) {
            int   sj = __builtin_amdgcn_readlane(s, j);
            float p = readlane_f(w0, j), q = readlane_f(w1, j);
            unsigned u = hpk[(size_t)sj * 64 + lane];
            acc0 = fmaf(p, bf_lo(u), acc0);
            acc1 = fmaf(q, bf_hi(u), acc1);
        }
    }
    float o0 = acc0 / (sum0 + 1e-16f) + bias[lane];
    float o1 = acc1 / (sum1 + 1e-16f) + bias[64 + lane];
    out1b[(size_t)node * 128 + lane]      = f2bf(fmaxf(o0, 0.f));
    out1b[(size_t)node * 128 + 64 + lane] = f2bf(fmaxf(o1, 0.f));
}

// ---------------------------------------------------------------- agg layer2: no-max, bf16 gather, no relu
__global__ void agg_layer2(const unsigned short* __restrict__ hb, const float* __restrict__ asrc,
                           const float* __restrict__ adst, const int* __restrict__ offs,
                           const int* __restrict__ csr, const float* __restrict__ bias,
                           float* __restrict__ out, int N) {
    int node = (blockIdx.x * blockDim.x + threadIdx.x) >> 6;
    int lane = threadIdx.x & 63;
    if (node >= N) return;
    int off = offs[node], end = offs[node + 1];
    float ad = adst[node];
    float wself = __expf(fminf(LEAKY(asrc[node] + ad), 60.f));
    float sum = wself;
    float acc = wself * __uint_as_float((unsigned)hb[(size_t)node * 64 + lane] << 16);

    for (int chunk = off; chunk < end; chunk += 64) {
        int e = chunk + lane;
        int s = 0;
        float w = 0.f;
        if (e < end) {
            s = __builtin_nontemporal_load(&csr[e]);
            w = __expf(fminf(LEAKY(asrc[s] + ad), 60.f));
        }
        float t = w;
#pragma unroll
        for (int o = 32; o > 0; o >>= 1) t += __shfl_xor(t, o);
        sum += t;

        int cnt = min(64, end - chunk);
        int j = 0;
        for (; j + 4 <= cnt; j += 4) {
            int   sj0 = __builtin_amdgcn_readlane(s, j);
            int   sj1 = __builtin_amdgcn_readlane(s, j + 1);
            int   sj2 = __builtin_amdgcn_readlane(s, j + 2);
            int   sj3 = __builtin_amdgcn_readlane(s, j + 3);
            float p0 = readlane_f(w, j);
            float p1 = readlane_f(w, j + 1);
            float p2 = readlane_f(w, j + 2);
            float p3 = readlane_f(w, j + 3);
            float v0 = __uint_as_float((unsigned)hb[(size_t)sj0 * 64 + lane] << 16);
            float v1 = __uint_as_float((unsigned)hb[(size_t)sj1 * 64 + lane] << 16);
            float v2 = __uint_as_float((unsigned)hb[(size_t)sj2 * 64 + lane] << 16);
            float v3 = __uint_as_float((unsigned)hb[(size_t)sj3 * 64 + lane] << 16);
            acc = fmaf(p0, v0, acc);
            acc = fmaf(p1, v1, acc);
            acc = fmaf(p2, v2, acc);
            acc = fmaf(p3, v3, acc);
        }
        for (; j < cnt; ++j) {
            int   sj = __builtin_amdgcn_readlane(s, j);
            float p = readlane_f(w, j);
            acc = fmaf(p, __uint_as_float((unsigned)hb[(size_t)sj * 64 + lane] << 16), acc);
        }
    }
    out[(size_t)node * 64 + lane] = acc / (sum + 1e-16f) + bias[lane];
}

// ---------------------------------------------------------------- host
extern "C" void kernel_launch(void* const* d_in, const int* in_sizes, int n_in,
                              void* d_out, int out_size, void* d_ws, size_t ws_size,
                              hipStream_t stream) {
    const float* x        = (const float*)d_in[0];
    const int* ei         = (const int*)d_in[1];
    const float* W1       = (const float*)d_in[2];
    const float* att_src1 = (const float*)d_in[3];
    const float* att_dst1 = (const float*)d_in[4];
    const float* bias1    = (const float*)d_in[5];
    const float* W2       = (const float*)d_in[6];
    const float* att_src2 = (const float*)d_in[7];
    const float* att_dst2 = (const float*)d_in[8];
    const float* bias2    = (const float*)d_in[9];

    const int N = in_sizes[0] / 128;  // 100000
    const int E = in_sizes[1] / 2;    // 1600000

    char* base = (char*)d_ws;
    size_t off = 0;
    auto alloc = [&](size_t bytes) {
        char* p = base + off;
        off = (off + bytes + 255) & ~(size_t)255;
        return p;
    };
    const int nbuckets = (N + (1 << BSH) - 1) >> BSH; // 196
    int*      bcur    = (int*)alloc((size_t)NBUCK * BPAD * 4 + 256);  // + ocnt tail
    int*      ocnt    = bcur + NBUCK * BPAD;
    int*      offsets = (int*)alloc((size_t)(N + 1) * 4);
    int*      csr     = (int*)alloc((size_t)E * 4);
    int2*     ebuf    = (int2*)alloc((size_t)nbuckets * CAP * 8);
    int2*     obuf    = (int2*)alloc((size_t)65536 * 8);
    unsigned* hpk     = (unsigned*)alloc((size_t)N * 64 * 4);        // packed bf16 pairs L1
    unsigned short* hb    = (unsigned short*)alloc((size_t)N * 64 * 2);  // bf16 L2 features
    unsigned short* out1b = (unsigned short*)alloc((size_t)N * 128 * 2); // L1 output, bf16
    float*    asrc1   = (float*)alloc((size_t)N * 2 * 4);
    float*    adst1   = (float*)alloc((size_t)N * 2 * 4);
    float*    asrc2   = (float*)alloc((size_t)N * 4);
    float*    adst2   = (float*)alloc((size_t)N * 4);

    const int mblocks64 = (N + 63) / 64;              // 1563
    const int nwave_blocks = (N + 3) / 4;
    const int p1Blocks = (E + 4095) / 4096;           // 391

    // --- zero bucket cursors + overflow counter ---
    hipMemsetAsync(bcur, 0, (size_t)NBUCK * BPAD * 4 + 256, stream);

    // --- K1: MFMA GEMM1+epilogue || pass1 fixed-cap edge binning ---
    fused_gemm1_pass1<<<p1Blocks + mblocks64, 256, 0, stream>>>(
        x, W1, N, att_src1, att_dst1, hpk, asrc1, adst1, ei, E, bcur, ebuf, obuf, ocnt,
        p1Blocks);

    // --- K2: per-bucket offsets + localized scatter ---
    pass2_build<<<nbuckets, 256, 0, stream>>>(ebuf, bcur, obuf, ocnt, offsets, csr, N, nbuckets);

    // --- layer 1 aggregate (writes bf16) ---
    agg_layer1<<<nwave_blocks, 256, 0, stream>>>(hpk, asrc1, adst1, offsets, csr, bias1, out1b, N);

    // --- K3: MFMA GEMM2+epilogue ---
    gemm2_epi<<<mblocks64, 256, 0, stream>>>(out1b, W2, N, att_src2, att_dst2, hb, asrc2, adst2);

    // --- layer 2 aggregate ---
    agg_layer2<<<nwave_blocks, 256, 0, stream>>>(hb, asrc2, adst2, offsets, csr, bias2,
                                                 (float*)d_out, N);
}

// Round 16
// 217.705 us; speedup vs baseline: 1.1231x; 1.0005x over previous
//
#include <hip/hip_runtime.h>
#include <hip/hip_bf16.h>
#include <cstdint>
#include <cstddef>

#define LEAKY(x) ((x) > 0.f ? (x) : 0.2f * (x))

#define NBUCK 256          // bucket array size (196 used: 512-node buckets)
#define BSH   9            // bucket shift
#define BPAD  16           // pad counters one 64B line apart
#define CAP   16384        // fixed edge capacity per bucket (mean 8163, 46-sigma margin)
#define WPAD  136          // LDS W row pad (272B stride)

typedef float        f32x4  __attribute__((ext_vector_type(4)));
typedef unsigned int u32x4  __attribute__((ext_vector_type(4)));
typedef short        bf16x8 __attribute__((ext_vector_type(8)));

__device__ __forceinline__ float readlane_f(float v, int l) {
    return __int_as_float(__builtin_amdgcn_readlane(__float_as_int(v), l));
}
__device__ __forceinline__ unsigned short f2bf(float f) {
    unsigned x = __float_as_uint(f);
    return (unsigned short)((x + 0x7fffu + ((x >> 16) & 1u)) >> 16);
}
__device__ __forceinline__ float bf_lo(unsigned u) { return __uint_as_float(u << 16); }
__device__ __forceinline__ float bf_hi(unsigned u) { return __uint_as_float(u & 0xffff0000u); }

__device__ __forceinline__ bf16x8 as_bf16x8(u32x4 u) {
    union { u32x4 u4; bf16x8 b; } cv;
    cv.u4 = u;
    return cv.b;
}

// ---------------------------------------------------------------- W pre-convert: fp32 -> bf16, transposed + padded to LDS layout
__global__ void convert_W(const float* __restrict__ W1, const float* __restrict__ W2,
                          unsigned short* __restrict__ W1p, unsigned short* __restrict__ W2p) {
    int idx = blockIdx.x * 256 + threadIdx.x;
    if (idx < 16384) {                       // W1 [128][128] -> W1p[c*WPAD+k]
        int c = idx >> 7, k = idx & 127;
        W1p[c * WPAD + k] = f2bf(W1[k * 128 + c]);
    }
    int i2 = idx - 16384;
    if (i2 >= 0 && i2 < 8192) {              // W2 [128][64] -> W2p[c*WPAD+k]
        int c = i2 & 63, k = i2 >> 6;
        W2p[c * WPAD + k] = f2bf(W2[k * 64 + c]);
    }
}

// ---------------------------------------------------------------- K1: pass1 (fixed-cap binning) || MFMA GEMM1 + epilogue
__global__ __launch_bounds__(256) void fused_gemm1_pass1(
    const float* __restrict__ x, const unsigned short* __restrict__ W1p, int M,
    const float* __restrict__ att_src, const float* __restrict__ att_dst,
    unsigned* __restrict__ hpk, float* __restrict__ asrc, float* __restrict__ adst,
    const int* __restrict__ ei, int E, int* __restrict__ bcur, int2* __restrict__ ebuf,
    int2* __restrict__ obuf, int* __restrict__ ocnt, int p1Blocks) {
    const int tid = threadIdx.x;
    if ((int)blockIdx.x < p1Blocks) {
        __shared__ int bcnt_l[NBUCK];
        __shared__ int bbase_l[NBUCK];
        const int e0 = (int)blockIdx.x * 4096;
        const int ecnt = min(4096, E - e0);
        for (int i = tid; i < NBUCK; i += 256) bcnt_l[i] = 0;
        __syncthreads();
        for (int i = tid; i < ecnt; i += 256)
            atomicAdd(&bcnt_l[ei[E + e0 + i] >> BSH], 1);
        __syncthreads();
        if (tid < NBUCK) {
            int c = bcnt_l[tid];
            bbase_l[tid] = c ? atomicAdd(&bcur[tid * BPAD], c) : 0;
            bcnt_l[tid] = 0;
        }
        __syncthreads();
        for (int i = tid; i < ecnt; i += 256) {
            int s = ei[e0 + i];
            int d = ei[E + e0 + i];
            int b = d >> BSH;
            int l = atomicAdd(&bcnt_l[b], 1);
            int g = bbase_l[b] + l;
            if (g < CAP) {
                ebuf[(size_t)b * CAP + g] = make_int2(s, d);
            } else {
                int oi = atomicAdd(ocnt, 1);
                obuf[oi & 65535] = make_int2(s, d);
            }
        }
    } else {
        __shared__ unsigned short Wt[128][WPAD];   // [col][k], bf16 (straight copy of W1p)
        for (int i = tid * 8; i + 8 <= 128 * WPAD; i += 2048)
            *(u32x4*)&Wt[0][i] = *(const u32x4*)&W1p[i];
        __syncthreads();
        const int gb = (int)blockIdx.x - p1Blocks;
        const int lane = tid & 63;
        const int li = lane & 15, g = lane >> 4;
        const int row0 = gb * 64 + (tid >> 6) * 16;
        const int arow = min(row0 + li, M - 1);
        f32x4 acc[8];
#pragma unroll
        for (int ct = 0; ct < 8; ++ct) acc[ct] = (f32x4)(0.f);
        const float* ap = x + (size_t)arow * 128 + g * 8;
#pragma unroll
        for (int ks = 0; ks < 4; ++ks) {
            float4 a0 = *(const float4*)(ap + ks * 32);
            float4 a1 = *(const float4*)(ap + ks * 32 + 4);
            u32x4 af;
            af.x = (unsigned)f2bf(a0.x) | ((unsigned)f2bf(a0.y) << 16);
            af.y = (unsigned)f2bf(a0.z) | ((unsigned)f2bf(a0.w) << 16);
            af.z = (unsigned)f2bf(a1.x) | ((unsigned)f2bf(a1.y) << 16);
            af.w = (unsigned)f2bf(a1.z) | ((unsigned)f2bf(a1.w) << 16);
            bf16x8 av = as_bf16x8(af);
#pragma unroll
            for (int ct = 0; ct < 8; ++ct) {
                bf16x8 bv = *(const bf16x8*)&Wt[ct * 16 + li][ks * 32 + g * 8];
                acc[ct] = __builtin_amdgcn_mfma_f32_16x16x32_bf16(av, bv, acc[ct], 0, 0, 0);
            }
        }
        float asv[8], adv[8];
#pragma unroll
        for (int ct = 0; ct < 8; ++ct) {
            asv[ct] = att_src[ct * 16 + li];
            adv[ct] = att_dst[ct * 16 + li];
        }
#pragma unroll
        for (int reg = 0; reg < 4; ++reg) {
            int r = row0 + g * 4 + reg;
            float ps0 = 0.f, pd0 = 0.f, ps1 = 0.f, pd1 = 0.f;
#pragma unroll
            for (int ct = 0; ct < 4; ++ct) {
                ps0 = fmaf(acc[ct][reg], asv[ct], ps0);
                pd0 = fmaf(acc[ct][reg], adv[ct], pd0);
                ps1 = fmaf(acc[ct + 4][reg], asv[ct + 4], ps1);
                pd1 = fmaf(acc[ct + 4][reg], adv[ct + 4], pd1);
            }
#pragma unroll
            for (int m = 8; m > 0; m >>= 1) {
                ps0 += __shfl_xor(ps0, m);
                pd0 += __shfl_xor(pd0, m);
                ps1 += __shfl_xor(ps1, m);
                pd1 += __shfl_xor(pd1, m);
            }
            if (r < M) {
                if (li == 0) {
                    asrc[2 * r] = ps0; asrc[2 * r + 1] = ps1;
                    adst[2 * r] = pd0; adst[2 * r + 1] = pd1;
                }
#pragma unroll
                for (int ct = 0; ct < 4; ++ct)
                    hpk[(size_t)r * 64 + ct * 16 + li] =
                        (unsigned)f2bf(acc[ct][reg]) | ((unsigned)f2bf(acc[ct + 4][reg]) << 16);
            }
        }
    }
}

// ---------------------------------------------------------------- K2: per-bucket offsets + localized scatter
__global__ __launch_bounds__(256) void pass2_build(
    const int2* __restrict__ ebuf, const int* __restrict__ bcur,
    const int2* __restrict__ obuf, const int* __restrict__ ocnt,
    int* __restrict__ offsets, int* __restrict__ csr, int N, int nbuckets) {
    __shared__ int lcur[1 << BSH];
    __shared__ int ssum[256];
    __shared__ int cnts[NBUCK];
    __shared__ int prefix_s;
    const int b = blockIdx.x;
    const int dbase = b << BSH;
    const int tid = threadIdx.x;
    if (tid < NBUCK) cnts[tid] = (tid < nbuckets) ? bcur[tid * BPAD] : 0;
    for (int i = tid; i < (1 << BSH); i += 256) lcur[i] = 0;
    __syncthreads();
    if (tid == 0) {
        int p = 0;
        for (int i = 0; i < b; ++i) p += cnts[i];
        prefix_s = p;
    }
    const int tc = cnts[b];
    const int ec = min(tc, CAP);
    const int2* eb = ebuf + (size_t)b * CAP;
    for (int i = tid; i < ec; i += 256)
        atomicAdd(&lcur[eb[i].y - dbase], 1);
    const int no = (tc > CAP) ? min(*ocnt, 65536) : 0;
    for (int i = tid; i < no; i += 256) {
        int2 p = obuf[i];
        if ((p.y >> BSH) == b) atomicAdd(&lcur[p.y - dbase], 1);
    }
    __syncthreads();
    const int base_ = tid * 2;
    int v0 = lcur[base_], v1 = lcur[base_ + 1];
    ssum[tid] = v0 + v1;
    __syncthreads();
    for (int o = 1; o < 256; o <<= 1) {
        int add = (tid >= o) ? ssum[tid - o] : 0;
        __syncthreads();
        ssum[tid] += add;
        __syncthreads();
    }
    int excl = (tid ? ssum[tid - 1] : 0) + prefix_s;
    int c0 = excl, c1 = c0 + v0;
    lcur[base_] = c0; lcur[base_ + 1] = c1;
    int idx = dbase + base_;
    if (idx < N)     offsets[idx] = c0;
    if (idx + 1 < N) offsets[idx + 1] = c1;
    if (tid == 0 && b == nbuckets - 1) offsets[N] = prefix_s + tc;
    __syncthreads();
    for (int i = tid; i < ec; i += 256) {
        int2 p = eb[i];
        int pos = atomicAdd(&lcur[p.y - dbase], 1);
        csr[pos] = p.x;
    }
    for (int i = tid; i < no; i += 256) {
        int2 p = obuf[i];
        if ((p.y >> BSH) == b) {
            int pos = atomicAdd(&lcur[p.y - dbase], 1);
            csr[pos] = p.x;
        }
    }
}

// ---------------------------------------------------------------- K3: MFMA GEMM2 + epilogue
__global__ __launch_bounds__(256) void gemm2_epi(
    const unsigned short* __restrict__ A, const unsigned short* __restrict__ W2p, int M,
    const float* __restrict__ att_src, const float* __restrict__ att_dst,
    unsigned short* __restrict__ hb, float* __restrict__ asrc, float* __restrict__ adst) {
    __shared__ unsigned short Wt[64][WPAD];
    const int tid = threadIdx.x;
    for (int i = tid * 8; i + 8 <= 64 * WPAD; i += 2048)
        *(u32x4*)&Wt[0][i] = *(const u32x4*)&W2p[i];
    __syncthreads();
    const int lane = tid & 63;
    const int li = lane & 15, g = lane >> 4;
    const int row0 = blockIdx.x * 64 + (tid >> 6) * 16;
    const int arow = min(row0 + li, M - 1);
    f32x4 acc[4];
#pragma unroll
    for (int ct = 0; ct < 4; ++ct) acc[ct] = (f32x4)(0.f);
    const unsigned short* ap = A + (size_t)arow * 128 + g * 8;
#pragma unroll
    for (int ks = 0; ks < 4; ++ks) {
        bf16x8 av = *(const bf16x8*)(ap + ks * 32);
#pragma unroll
        for (int ct = 0; ct < 4; ++ct) {
            bf16x8 bv = *(const bf16x8*)&Wt[ct * 16 + li][ks * 32 + g * 8];
            acc[ct] = __builtin_amdgcn_mfma_f32_16x16x32_bf16(av, bv, acc[ct], 0, 0, 0);
        }
    }
    float asv[4], adv[4];
#pragma unroll
    for (int ct = 0; ct < 4; ++ct) {
        asv[ct] = att_src[ct * 16 + li];
        adv[ct] = att_dst[ct * 16 + li];
    }
#pragma unroll
    for (int reg = 0; reg < 4; ++reg) {
        int r = row0 + g * 4 + reg;
        float ps = 0.f, pd = 0.f;
#pragma unroll
        for (int ct = 0; ct < 4; ++ct) {
            ps = fmaf(acc[ct][reg], asv[ct], ps);
            pd = fmaf(acc[ct][reg], adv[ct], pd);
        }
#pragma unroll
        for (int m = 8; m > 0; m >>= 1) {
            ps += __shfl_xor(ps, m);
            pd += __shfl_xor(pd, m);
        }
        if (r < M) {
            if (li == 0) { asrc[r] = ps; adst[r] = pd; }
#pragma unroll
            for (int ct = 0; ct < 4; ++ct)
                hb[(size_t)r * 64 + ct * 16 + li] = f2bf(acc[ct][reg]);
        }
    }
}

// ---------------------------------------------------------------- agg layer1: no-max softmax + aggregate, bf16 out
__global__ void agg_layer1(const unsigned* __restrict__ hpk, const float* __restrict__ asrc,
                           const float* __restrict__ adst, const int* __restrict__ offs,
                           const int* __restrict__ csr, const float* __restrict__ bias,
                           unsigned short* __restrict__ out1b, int N) {
    int node = (blockIdx.x * blockDim.x + threadIdx.x) >> 6;
    int lane = threadIdx.x & 63;
    if (node >= N) return;
    int off = offs[node], end = offs[node + 1];
    float ad0 = adst[2 * node], ad1 = adst[2 * node + 1];
    float ws0 = __expf(fminf(LEAKY(asrc[2 * node] + ad0), 60.f));
    float ws1 = __expf(fminf(LEAKY(asrc[2 * node + 1] + ad1), 60.f));
    float sum0 = ws0, sum1 = ws1;
    float acc0, acc1;
    {
        unsigned u = hpk[(size_t)node * 64 + lane];
        acc0 = ws0 * bf_lo(u);
        acc1 = ws1 * bf_hi(u);
    }
    for (int chunk = off; chunk < end; chunk += 64) {
        int e = chunk + lane;
        int s = 0;
        float w0 = 0.f, w1 = 0.f;
        if (e < end) {
            s = __builtin_nontemporal_load(&csr[e]);
            float2 as = *(const float2*)&asrc[2 * s];
            w0 = __expf(fminf(LEAKY(as.x + ad0), 60.f));
            w1 = __expf(fminf(LEAKY(as.y + ad1), 60.f));
        }
        float t0 = w0, t1 = w1;
#pragma unroll
        for (int o = 32; o > 0; o >>= 1) {
            t0 += __shfl_xor(t0, o);
            t1 += __shfl_xor(t1, o);
        }
        sum0 += t0; sum1 += t1;

        int cnt = min(64, end - chunk);
        int j = 0;
        for (; j + 4 <= cnt; j += 4) {
            int   sj0 = __builtin_amdgcn_readlane(s, j);
            int   sj1 = __builtin_amdgcn_readlane(s, j + 1);
            int   sj2 = __builtin_amdgcn_readlane(s, j + 2);
            int   sj3 = __builtin_amdgcn_readlane(s, j + 3);
            float p0 = readlane_f(w0, j),     q0 = readlane_f(w1, j);
            float p1 = readlane_f(w0, j + 1), q1 = readlane_f(w1, j + 1);
            float p2 = readlane_f(w0, j + 2), q2 = readlane_f(w1, j + 2);
            float p3 = readlane_f(w0, j + 3), q3 = readlane_f(w1, j + 3);
            unsigned u0 = hpk[(size_t)sj0 * 64 + lane];
            unsigned u1 = hpk[(size_t)sj1 * 64 + lane];
            unsigned u2 = hpk[(size_t)sj2 * 64 + lane];
            unsigned u3 = hpk[(size_t)sj3 * 64 + lane];
            acc0 = fmaf(p0, bf_lo(u0), acc0); acc1 = fmaf(q0, bf_hi(u0), acc1);
            acc0 = fmaf(p1, bf_lo(u1), acc0); acc1 = fmaf(q1, bf_hi(u1), acc1);
            acc0 = fmaf(p2, bf_lo(u2), acc0); acc1 = fmaf(q2, bf_hi(u2), acc1);
            acc0 = fmaf(p3, bf_lo(u3), acc0); acc1 = fmaf(q3, bf_hi(u3), acc1);
        }
        for (; j < cnt; ++j) {
            int   sj = __builtin_amdgcn_readlane(s, j);
            float p = readlane_f(w0, j), q = readlane_f(w1, j);
            unsigned u = hpk[(size_t)sj * 64 + lane];
            acc0 = fmaf(p, bf_lo(u), acc0);
            acc1 = fmaf(q, bf_hi(u), acc1);
        }
    }
    float o0 = acc0 / (sum0 + 1e-16f) + bias[lane];
    float o1 = acc1 / (sum1 + 1e-16f) + bias[64 + lane];
    out1b[(size_t)node * 128 + lane]      = f2bf(fmaxf(o0, 0.f));
    out1b[(size_t)node * 128 + 64 + lane] = f2bf(fmaxf(o1, 0.f));
}

// ---------------------------------------------------------------- agg layer2: no-max, bf16 gather, no relu
__global__ void agg_layer2(const unsigned short* __restrict__ hb, const float* __restrict__ asrc,
                           const float* __restrict__ adst, const int* __restrict__ offs,
                           const int* __restrict__ csr, const float* __restrict__ bias,
                           float* __restrict__ out, int N) {
    int node = (blockIdx.x * blockDim.x + threadIdx.x) >> 6;
    int lane = threadIdx.x & 63;
    if (node >= N) return;
    int off = offs[node], end = offs[node + 1];
    float ad = adst[node];
    float wself = __expf(fminf(LEAKY(asrc[node] + ad), 60.f));
    float sum = wself;
    float acc = wself * __uint_as_float((unsigned)hb[(size_t)node * 64 + lane] << 16);

    for (int chunk = off; chunk < end; chunk += 64) {
        int e = chunk + lane;
        int s = 0;
        float w = 0.f;
        if (e < end) {
            s = __builtin_nontemporal_load(&csr[e]);
            w = __expf(fminf(LEAKY(asrc[s] + ad), 60.f));
        }
        float t = w;
#pragma unroll
        for (int o = 32; o > 0; o >>= 1) t += __shfl_xor(t, o);
        sum += t;

        int cnt = min(64, end - chunk);
        int j = 0;
        for (; j + 4 <= cnt; j += 4) {
            int   sj0 = __builtin_amdgcn_readlane(s, j);
            int   sj1 = __builtin_amdgcn_readlane(s, j + 1);
            int   sj2 = __builtin_amdgcn_readlane(s, j + 2);
            int   sj3 = __builtin_amdgcn_readlane(s, j + 3);
            float p0 = readlane_f(w, j);
            float p1 = readlane_f(w, j + 1);
            float p2 = readlane_f(w, j + 2);
            float p3 = readlane_f(w, j + 3);
            float v0 = __uint_as_float((unsigned)hb[(size_t)sj0 * 64 + lane] << 16);
            float v1 = __uint_as_float((unsigned)hb[(size_t)sj1 * 64 + lane] << 16);
            float v2 = __uint_as_float((unsigned)hb[(size_t)sj2 * 64 + lane] << 16);
            float v3 = __uint_as_float((unsigned)hb[(size_t)sj3 * 64 + lane] << 16);
            acc = fmaf(p0, v0, acc);
            acc = fmaf(p1, v1, acc);
            acc = fmaf(p2, v2, acc);
            acc = fmaf(p3, v3, acc);
        }
        for (; j < cnt; ++j) {
            int   sj = __builtin_amdgcn_readlane(s, j);
            float p = readlane_f(w, j);
            acc = fmaf(p, __uint_as_float((unsigned)hb[(size_t)sj * 64 + lane] << 16), acc);
        }
    }
    out[(size_t)node * 64 + lane] = acc / (sum + 1e-16f) + bias[lane];
}

// ---------------------------------------------------------------- host
extern "C" void kernel_launch(void* const* d_in, const int* in_sizes, int n_in,
                              void* d_out, int out_size, void* d_ws, size_t ws_size,
                              hipStream_t stream) {
    const float* x        = (const float*)d_in[0];
    const int* ei         = (const int*)d_in[1];
    const float* W1       = (const float*)d_in[2];
    const float* att_src1 = (const float*)d_in[3];
    const float* att_dst1 = (const float*)d_in[4];
    const float* bias1    = (const float*)d_in[5];
    const float* W2       = (const float*)d_in[6];
    const float* att_src2 = (const float*)d_in[7];
    const float* att_dst2 = (const float*)d_in[8];
    const float* bias2    = (const float*)d_in[9];

    const int N = in_sizes[0] / 128;  // 100000
    const int E = in_sizes[1] / 2;    // 1600000

    char* base = (char*)d_ws;
    size_t off = 0;
    auto alloc = [&](size_t bytes) {
        char* p = base + off;
        off = (off + bytes + 255) & ~(size_t)255;
        return p;
    };
    const int nbuckets = (N + (1 << BSH) - 1) >> BSH; // 196
    int*      bcur    = (int*)alloc((size_t)NBUCK * BPAD * 4 + 256);  // + ocnt tail
    int*      ocnt    = bcur + NBUCK * BPAD;
    int*      offsets = (int*)alloc((size_t)(N + 1) * 4);
    int*      csr     = (int*)alloc((size_t)E * 4);
    int2*     ebuf    = (int2*)alloc((size_t)nbuckets * CAP * 8);
    int2*     obuf    = (int2*)alloc((size_t)65536 * 8);
    unsigned* hpk     = (unsigned*)alloc((size_t)N * 64 * 4);        // packed bf16 pairs L1
    unsigned short* hb    = (unsigned short*)alloc((size_t)N * 64 * 2);  // bf16 L2 features
    unsigned short* out1b = (unsigned short*)alloc((size_t)N * 128 * 2); // L1 output, bf16
    unsigned short* W1p   = (unsigned short*)alloc((size_t)128 * WPAD * 2);
    unsigned short* W2p   = (unsigned short*)alloc((size_t)64 * WPAD * 2);
    float*    asrc1   = (float*)alloc((size_t)N * 2 * 4);
    float*    adst1   = (float*)alloc((size_t)N * 2 * 4);
    float*    asrc2   = (float*)alloc((size_t)N * 4);
    float*    adst2   = (float*)alloc((size_t)N * 4);

    const int mblocks64 = (N + 63) / 64;              // 1563
    const int nwave_blocks = (N + 3) / 4;
    const int p1Blocks = (E + 4095) / 4096;           // 391

    // --- zero bucket cursors + overflow counter; pre-convert W ---
    hipMemsetAsync(bcur, 0, (size_t)NBUCK * BPAD * 4 + 256, stream);
    convert_W<<<96, 256, 0, stream>>>(W1, W2, W1p, W2p);

    // --- K1: MFMA GEMM1+epilogue || pass1 fixed-cap edge binning ---
    fused_gemm1_pass1<<<p1Blocks + mblocks64, 256, 0, stream>>>(
        x, W1p, N, att_src1, att_dst1, hpk, asrc1, adst1, ei, E, bcur, ebuf, obuf, ocnt,
        p1Blocks);

    // --- K2: per-bucket offsets + localized scatter ---
    pass2_build<<<nbuckets, 256, 0, stream>>>(ebuf, bcur, obuf, ocnt, offsets, csr, N, nbuckets);

    // --- layer 1 aggregate (writes bf16) ---
    agg_layer1<<<nwave_blocks, 256, 0, stream>>>(hpk, asrc1, adst1, offsets, csr, bias1, out1b, N);

    // --- K3: MFMA GEMM2+epilogue ---
    gemm2_epi<<<mblocks64, 256, 0, stream>>>(out1b, W2p, N, att_src2, att_dst2, hb, asrc2, adst2);

    // --- layer 2 aggregate ---
    agg_layer2<<<nwave_blocks, 256, 0, stream>>>(hb, asrc2, adst2, offsets, csr, bias2,
                                                 (float*)d_out, N);
}